// Round 1
// 1608.660 us; speedup vs baseline: 1.2159x; 1.2159x over previous
//
#include <hip/hip_runtime.h>
#include <hip/hip_bf16.h>
#include <cstdint>
#include <cstddef>

// ---------------------------------------------------------------------------
// ViT block: x = image + attn(LN(image)); out = x + MLP(LN(x))
// B=1024 S=64 E=768 H=12 DH=64 HID=3072.  All GEMMs bf16 MFMA 16x16x32,
// fp32 accumulate; residual spine fp32.
// R3: GEMMs rewritten to the 256x256 8-phase schedule (T1+T2+T3+T4+T5):
//   - 512 thr / 8 waves (2Mx4N), per-wave C = two 64-row strips x 64 cols
//   - LDS 128KiB: 2 K-tile dbuf x {A,B} x 256x64 bf16, global_load_lds w=16,
//     pre-swizzled GLOBAL source + (slot ^ row&7) swizzled ds_read (rule #21)
//   - 4 phases/K-tile: {ds_read || 1 half-tile prefetch; s_barrier;
//     lgkmcnt(0); setprio(1); 16 MFMA; setprio(0); barrier}
//   - counted vmcnt(2) once per K-tile (never 0 in steady state)
//   - issue map: p1 Ah1(g+1), p2 Bh0(g+1), p3 Bh1(g+1), p4 Ah0(g+2);
//     each region proven dead at issue (A strips die at phase 2/4, B LDS
//     dies after phase 1 since B frags are register-cached per K-tile)
// ---------------------------------------------------------------------------

typedef __bf16 bf16;
typedef __bf16 bf16x8 __attribute__((ext_vector_type(8)));
typedef __bf16 bf16x4 __attribute__((ext_vector_type(4)));
typedef float  f32x4  __attribute__((ext_vector_type(4)));

#define LDS_ASYNC16(lds, g)                                                     \
  __builtin_amdgcn_global_load_lds(                                             \
      (const __attribute__((address_space(1))) void*)(g),                       \
      (__attribute__((address_space(3))) void*)(lds), 16, 0, 0)

#define NROWS 65536   // B*S
#define E_DIM 768
#define HID_DIM 3072
#define HEADS 12
#define QKV_N 2304    // 3*E

// ---------------------------------------------------------------------------
// transpose + fp32->bf16 cast:  in [K,N] row-major -> out [N,K] row-major
// ---------------------------------------------------------------------------
__global__ __launch_bounds__(256) void transpose_cast(
    const float* __restrict__ in, bf16* __restrict__ out, int K, int N) {
  __shared__ float tile[32][33];
  int tx = threadIdx.x & 31, ty = threadIdx.x >> 5;  // 32 x 8
  int n0 = blockIdx.x * 32, k0 = blockIdx.y * 32;
#pragma unroll
  for (int i = 0; i < 4; ++i)
    tile[ty + 8 * i][tx] = in[(size_t)(k0 + ty + 8 * i) * N + n0 + tx];
  __syncthreads();
#pragma unroll
  for (int i = 0; i < 4; ++i)
    out[(size_t)(n0 + ty + 8 * i) * K + k0 + tx] = (bf16)tile[tx][ty + 8 * i];
}

__global__ __launch_bounds__(256) void pack_bias(
    const float* __restrict__ bq, const float* __restrict__ bk,
    const float* __restrict__ bv, float* __restrict__ o) {
  int i = blockIdx.x * 256 + threadIdx.x;  // grid 9 -> 2304
  const float* src = i < 768 ? bq : (i < 1536 ? bk : bv);
  o[i] = src[i & 767];  // 768-aligned sections
}

// ---------------------------------------------------------------------------
// LayerNorm over E=768, one wave per row, fp32 in -> bf16 out
// ---------------------------------------------------------------------------
__global__ __launch_bounds__(256) void ln_kernel(
    const float* __restrict__ x, const float* __restrict__ gam,
    const float* __restrict__ bet, bf16* __restrict__ out) {
  int row  = blockIdx.x * 4 + (threadIdx.x >> 6);
  int lane = threadIdx.x & 63;
  const float4* xr = (const float4*)(x + (size_t)row * E_DIM);
  float4 v[3];
  float s = 0.f, ss = 0.f;
#pragma unroll
  for (int i = 0; i < 3; ++i) {
    v[i] = xr[lane + 64 * i];
    s  += v[i].x + v[i].y + v[i].z + v[i].w;
    ss += v[i].x * v[i].x + v[i].y * v[i].y + v[i].z * v[i].z + v[i].w * v[i].w;
  }
#pragma unroll
  for (int m = 1; m < 64; m <<= 1) {
    s  += __shfl_xor(s, m);
    ss += __shfl_xor(ss, m);
  }
  float mean = s * (1.f / 768.f);
  float var  = ss * (1.f / 768.f) - mean * mean;
  float rstd = rsqrtf(var + 1e-6f);
  bf16x4* o = (bf16x4*)(out + (size_t)row * E_DIM);
#pragma unroll
  for (int i = 0; i < 3; ++i) {
    float4 g4 = ((const float4*)gam)[lane + 64 * i];
    float4 b4 = ((const float4*)bet)[lane + 64 * i];
    bf16x4 r;
    r[0] = (bf16)((v[i].x - mean) * rstd * g4.x + b4.x);
    r[1] = (bf16)((v[i].y - mean) * rstd * g4.y + b4.y);
    r[2] = (bf16)((v[i].z - mean) * rstd * g4.z + b4.z);
    r[3] = (bf16)((v[i].w - mean) * rstd * g4.w + b4.w);
    o[lane + 64 * i] = r;
  }
}

// ---------------------------------------------------------------------------
// Lean attention per (b,h): q,k,v tiles from packed qkv buffer, scores MFMA,
// softmax, V@P MFMA, +image residual.  S==DH==64 reshape identity:
// x_flat[b*49152 + h*4096 + s*64 + t] = image + attn[b,h,s,t]
// ---------------------------------------------------------------------------
__global__ __launch_bounds__(256) void attn_kernel(
    const bf16* __restrict__ qkv, const float* __restrict__ image,
    float* __restrict__ xout) {
  __shared__ __align__(16) bf16 qs[64 * 72];  // pad 72: 2-way = free
  __shared__ __align__(16) bf16 ks[64 * 72];
  __shared__ __align__(16) bf16 vs[64 * 72];
  __shared__ __align__(16) bf16 pT[64 * 72];

  const int t = threadIdx.x, w = t >> 6, lane = t & 63;
  const int quad = lane >> 4, l15 = lane & 15;
  const int h = blockIdx.x % HEADS, b = blockIdx.x / HEADS;

  const bf16* base = qkv + (size_t)(b * 64) * QKV_N + h * 64;
#pragma unroll
  for (int i = 0; i < 2; ++i) {
    int slot = i * 256 + t;          // 0..511
    int row = slot >> 3, c = (slot & 7) * 8;
    size_t go = (size_t)row * QKV_N + c;
    *(bf16x8*)&qs[row * 72 + c] = *(const bf16x8*)&base[go];
    *(bf16x8*)&ks[row * 72 + c] = *(const bf16x8*)&base[go + 768];
    *(bf16x8*)&vs[row * 72 + c] = *(const bf16x8*)&base[go + 1536];
  }
  __syncthreads();

  // scores = q @ k^T; wave w owns rows w*16..+16
  f32x4 sc[4] = {};
#pragma unroll
  for (int kk = 0; kk < 2; ++kk) {
    bf16x8 af = *(const bf16x8*)&qs[(w * 16 + l15) * 72 + kk * 32 + quad * 8];
#pragma unroll
    for (int ni = 0; ni < 4; ++ni) {
      bf16x8 bfr = *(const bf16x8*)&ks[(ni * 16 + l15) * 72 + kk * 32 + quad * 8];
      sc[ni] = __builtin_amdgcn_mfma_f32_16x16x32_bf16(af, bfr, sc[ni], 0, 0, 0);
    }
  }

  // scale by 1/sqrt(E) then softmax along t (row in one quad x 4 regs)
  const float inv_sqrt_e = 0.03608439182435161f;
#pragma unroll
  for (int r = 0; r < 4; ++r) {
    float s0 = sc[0][r] * inv_sqrt_e, s1 = sc[1][r] * inv_sqrt_e;
    float s2 = sc[2][r] * inv_sqrt_e, s3 = sc[3][r] * inv_sqrt_e;
    float mx = fmaxf(fmaxf(s0, s1), fmaxf(s2, s3));
    mx = fmaxf(mx, __shfl_xor(mx, 1));
    mx = fmaxf(mx, __shfl_xor(mx, 2));
    mx = fmaxf(mx, __shfl_xor(mx, 4));
    mx = fmaxf(mx, __shfl_xor(mx, 8));
    float e0 = __expf(s0 - mx), e1 = __expf(s1 - mx);
    float e2 = __expf(s2 - mx), e3 = __expf(s3 - mx);
    float sm = e0 + e1 + e2 + e3;
    sm += __shfl_xor(sm, 1);
    sm += __shfl_xor(sm, 2);
    sm += __shfl_xor(sm, 4);
    sm += __shfl_xor(sm, 8);
    float inv = 1.f / sm;
    sc[0][r] = e0 * inv; sc[1][r] = e1 * inv;
    sc[2][r] = e2 * inv; sc[3][r] = e3 * inv;
  }

  // store P transposed: pT[t][s]
#pragma unroll
  for (int ni = 0; ni < 4; ++ni) {
    int tc = ni * 16 + l15;
#pragma unroll
    for (int r = 0; r < 4; ++r) {
      int s = w * 16 + quad * 4 + r;
      pT[tc * 72 + s] = (bf16)sc[ni][r];
    }
  }
  __syncthreads();

  // attn[s][t] = sum_d v[s][d] * P[d][t]
  f32x4 ao[4] = {};
#pragma unroll
  for (int kk = 0; kk < 2; ++kk) {
    bf16x8 af = *(const bf16x8*)&vs[(w * 16 + l15) * 72 + kk * 32 + quad * 8];
#pragma unroll
    for (int ni = 0; ni < 4; ++ni) {
      bf16x8 bfr = *(const bf16x8*)&pT[(ni * 16 + l15) * 72 + kk * 32 + quad * 8];
      ao[ni] = __builtin_amdgcn_mfma_f32_16x16x32_bf16(af, bfr, ao[ni], 0, 0, 0);
    }
  }

  size_t base_o = (size_t)b * 49152 + (size_t)h * 4096;
#pragma unroll
  for (int ni = 0; ni < 4; ++ni) {
    int tc = ni * 16 + l15;
#pragma unroll
    for (int r = 0; r < 4; ++r) {
      int s = w * 16 + quad * 4 + r;
      size_t off = base_o + (size_t)s * 64 + tc;
      xout[off] = image[off] + ao[ni][r];
    }
  }
}

// ---------------------------------------------------------------------------
// fast GELU: tanh form, robust at +-inf (no inf/inf)
// ---------------------------------------------------------------------------
__device__ inline float gelu_f(float x) {
  float u = x * (0.7978845608028654f + 0.0356774081f * x * x);
  float e = __expf(2.f * u);
  float th = 1.f - 2.f / (e + 1.f);
  return 0.5f * x * (1.f + th);
}

__device__ __forceinline__ f32x4 mfma8(bf16x8 a, bf16x8 b, f32x4 c) {
  return __builtin_amdgcn_mfma_f32_16x16x32_bf16(a, b, c, 0, 0, 0);
}

#define LDF(P, OFF) (*(const bf16x8*)((P) + (OFF)))

// ---------------------------------------------------------------------------
// 256x256 8-phase GEMM:  C[M,N] = A[M,K] @ B^T  (B stored [N,K] bf16).
// Requires M%256==0, N%256==0, K%64==0, K>=128, grid = (N/256, M/256),
// nwg%8==0.  EPI 0: bias+GELU->bf16.  1: bias+resid->f32.  2: bias->bf16.
// ---------------------------------------------------------------------------
template <int EPI>
__global__ __launch_bounds__(512) void gemm256(
    const bf16* __restrict__ A, const bf16* __restrict__ B,
    const float* __restrict__ bias, bf16* __restrict__ outb, float* outf,
    const float* resid, int M, int N, int K) {
  __shared__ __align__(16) char lds[131072];  // A: 2x32KB @0, B: 2x32KB @64K
  const int t = threadIdx.x;
  const int wq = t >> 6, lane = t & 63;
  const int quad = lane >> 4, l15 = lane & 15;
  const int wm = wq >> 2, wn = wq & 3;  // 2 x 4 wave grid

  // T1: XCD-aware bijective swizzle (nwg % 8 == 0 for all launch shapes here)
  const int Ntile = (int)gridDim.x;
  const int nwg = Ntile * (int)gridDim.y;
  const int flat = (int)blockIdx.y * Ntile + (int)blockIdx.x;
  const int id2 = (flat & 7) * (nwg >> 3) + (flat >> 3);
  const int bn = id2 % Ntile, bm = id2 / Ntile;

  const int NT = K >> 6;  // K-tiles of 64
  const size_t rowK = (size_t)K;

  // Staging: per-thread pre-swizzled GLOBAL source (linear LDS dest).
  // dst byte t*16 -> tile row t>>3, slot t&7; phys slot holds logical
  // slot (t&7)^(row&7), so fetch that column from global.
  const int tr = t >> 3, ts = t & 7;
  const bf16* aSrc = A + ((size_t)bm * 256 + tr) * rowK + ((ts ^ (tr & 7)) << 3);
  const bf16* bSrc = B + ((size_t)bn * 256 + tr) * rowK + ((ts ^ (tr & 7)) << 3);

  char* ldsA = (char*)lds;
  char* ldsB = (char*)lds + 65536;
  const int stDst = wq * 1024;  // wave-uniform LDS base piece

  // stage one 128-row half-tile (2 x global_load_lds w=16; 512 thr x 16B x 2)
#define STAGE_H(LB, BUFP, H, SRC, KT)                                           \
  do {                                                                          \
    LDS_ASYNC16((LB) + (BUFP) * 32768 + ((H) * 128 + 0) * 128 + stDst,          \
                (SRC) + (size_t)((H) * 128 + 0) * rowK + (size_t)(KT) * 64);    \
    LDS_ASYNC16((LB) + (BUFP) * 32768 + ((H) * 128 + 64) * 128 + stDst,         \
                (SRC) + (size_t)((H) * 128 + 64) * rowK + (size_t)(KT) * 64);   \
  } while (0)

  // prologue: K-tile 0 -> buf0, K-tile 1 -> buf1 (16 loads); wait K0 only.
  STAGE_H(ldsA, 0, 0, aSrc, 0);
  STAGE_H(ldsA, 0, 1, aSrc, 0);
  STAGE_H(ldsB, 0, 0, bSrc, 0);
  STAGE_H(ldsB, 0, 1, bSrc, 0);
  STAGE_H(ldsA, 1, 0, aSrc, 1);
  STAGE_H(ldsA, 1, 1, aSrc, 1);
  STAGE_H(ldsB, 1, 0, bSrc, 1);
  STAGE_H(ldsB, 1, 1, bSrc, 1);
  asm volatile("s_waitcnt vmcnt(8)" ::: "memory");
  __builtin_amdgcn_s_barrier();

  // T2 read swizzle: logical 16B slot (kk*4+quad) ^ (row&7); row&7 == l15&7.
  const int sx = l15 & 7;
  const int c0 = (quad ^ sx) << 4;        // kk=0
  const int c1 = ((4 + quad) ^ sx) << 4;  // kk=1
  // A rows: strip s = mi>>2 at (s*128 + wm*64 + (mi&3)*16 + l15); *128 B/row
  const int arow = (wm * 64 + l15) * 128;
  const int brow = (wn * 64 + l15) * 128;

  f32x4 acc[8][4] = {};
  bf16x8 bReg[4][2];  // B frags register-cached per K-tile

  // one phase: 2 M-frags x 4 N-frags x kk{0,1} = 16 MFMA
#define GPHASE(OFF0, OFF1, M0, STAGE_STMT, TAIL_STMT)                           \
  do {                                                                          \
    bf16x8 a00 = LDF(Ab, (OFF0) + c0);                                          \
    bf16x8 a01 = LDF(Ab, (OFF0) + c1);                                          \
    bf16x8 a10 = LDF(Ab, (OFF1) + c0);                                          \
    bf16x8 a11 = LDF(Ab, (OFF1) + c1);                                          \
    STAGE_STMT;                                                                 \
    asm volatile("" ::: "memory");                                              \
    __builtin_amdgcn_s_barrier();                                               \
    asm volatile("s_waitcnt lgkmcnt(0)" ::: "memory");                          \
    __builtin_amdgcn_s_setprio(1);                                              \
    _Pragma("unroll")                                                           \
    for (int ni = 0; ni < 4; ++ni) {                                            \
      acc[(M0)][ni]     = mfma8(a00, bReg[ni][0], acc[(M0)][ni]);               \
      acc[(M0)][ni]     = mfma8(a01, bReg[ni][1], acc[(M0)][ni]);               \
      acc[(M0) + 1][ni] = mfma8(a10, bReg[ni][0], acc[(M0) + 1][ni]);           \
      acc[(M0) + 1][ni] = mfma8(a11, bReg[ni][1], acc[(M0) + 1][ni]);           \
    }                                                                           \
    __builtin_amdgcn_s_setprio(0);                                              \
    TAIL_STMT;                                                                  \
    __builtin_amdgcn_s_barrier();                                               \
  } while (0)

  for (int g = 0; g < NT; ++g) {
    const int bufp = g & 1;
    const char* Ab = ldsA + bufp * 32768;
    const char* Bb = ldsB + bufp * 32768;
    const int kn = g + 1, bnx = kn & 1;

    // B frags for this K-tile (12 ds_reads total in phase 1)
#pragma unroll
    for (int ni = 0; ni < 4; ++ni) {
      bReg[ni][0] = LDF(Bb, brow + ni * 2048 + c0);
      bReg[ni][1] = LDF(Bb, brow + ni * 2048 + c1);
    }
    // phase 1: mi {0,1} (strip0, A-half0).  Stage Ah1(g+1): dead since g-1 p4.
    GPHASE(arow, arow + 2048, 0,
           { if (g >= 1 && kn < NT) STAGE_H(ldsA, bnx, 1, aSrc, kn); }, {});
    // phase 2: mi {2,3}.  Stage Bh0(g+1): B LDS dead since g-1 phase 1.
    GPHASE(arow + 4096, arow + 6144, 2,
           { if (g >= 1 && kn < NT) STAGE_H(ldsB, bnx, 0, bSrc, kn); }, {});
    // phase 3: mi {4,5} (strip1, A-half1).  Stage Bh1(g+1).
    GPHASE(arow + 16384, arow + 18432, 4,
           { if (g >= 1 && kn < NT) STAGE_H(ldsB, bnx, 1, bSrc, kn); }, {});
    // phase 4: mi {6,7}.  Stage Ah0(g+2): this buf's half0 died after phase 2.
    // Boundary: counted vmcnt -- leave Ah0(g+2)'s 2 loads in flight.
    GPHASE(arow + 20480, arow + 22528, 6,
           { if (g + 2 < NT) STAGE_H(ldsA, bufp, 0, aSrc, g + 2); },
           {
             if (g < NT - 2)
               asm volatile("s_waitcnt vmcnt(2)" ::: "memory");
             else if (g == NT - 2)
               asm volatile("s_waitcnt vmcnt(0)" ::: "memory");
           });
  }
#undef GPHASE
#undef STAGE_H

  // epilogue: C[row,col], row = bm*256 + strip*128 + wm*64 + (mi&3)*16+quad*4+r
  const int row0 = bm * 256 + wm * 64 + quad * 4;
  const int col0 = bn * 256 + wn * 64 + l15;
#pragma unroll
  for (int mi = 0; mi < 8; ++mi) {
    const int rbase = row0 + (mi >> 2) * 128 + (mi & 3) * 16;
#pragma unroll
    for (int ni = 0; ni < 4; ++ni) {
      const int col = col0 + ni * 16;
      const float bc = bias[col];
#pragma unroll
      for (int r = 0; r < 4; ++r) {
        const int row = rbase + r;
        const float v = acc[mi][ni][r] + bc;
        const size_t off = (size_t)row * N + col;
        if (EPI == 0)      outb[off] = (bf16)gelu_f(v);
        else if (EPI == 1) outf[off] = resid[off] + v;
        else               outb[off] = (bf16)v;
      }
    }
  }
}

// ---------------------------------------------------------------------------
extern "C" void kernel_launch(void* const* d_in, const int* in_sizes, int n_in,
                              void* d_out, int out_size, void* d_ws,
                              size_t ws_size, hipStream_t stream) {
  const float* image = (const float*)d_in[0];
  const float* ln_g  = (const float*)d_in[1];
  const float* ln_b  = (const float*)d_in[2];
  const float* Wq    = (const float*)d_in[3];
  const float* bq    = (const float*)d_in[4];
  const float* Wk    = (const float*)d_in[5];
  const float* bk    = (const float*)d_in[6];
  const float* Wv    = (const float*)d_in[7];
  const float* bv    = (const float*)d_in[8];
  const float* W1    = (const float*)d_in[9];
  const float* b1    = (const float*)d_in[10];
  const float* W2    = (const float*)d_in[11];
  const float* b2    = (const float*)d_in[12];
  float* out = (float*)d_out;

  char* ws = (char*)d_ws;
  bf16* hn   = (bf16*)ws;  ws += (size_t)NROWS * E_DIM * 2;      // 100.7 MB
  // h1 (65536x3072 bf16, 402 MB) and qkv (65536x2304 bf16, 302 MB) have
  // disjoint live ranges -> alias the same region.
  bf16* h1   = (bf16*)ws;
  bf16* qkv  = (bf16*)ws;  ws += (size_t)NROWS * HID_DIM * 2;
  bf16* WqkvT = (bf16*)ws; ws += (size_t)QKV_N * E_DIM * 2;      // packed [2304,768]
  bf16* W1T  = (bf16*)ws;  ws += (size_t)E_DIM * HID_DIM * 2;
  bf16* W2T  = (bf16*)ws;  ws += (size_t)E_DIM * HID_DIM * 2;
  float* bqkv = (float*)ws; ws += QKV_N * 4;

  dim3 blk(256);
  dim3 blk512(512);
  // weights -> bf16 [N,K]; Wq|Wk|Wv packed into one [2304,768]
  transpose_cast<<<dim3(24, 24), blk, 0, stream>>>(Wq, WqkvT, 768, 768);
  transpose_cast<<<dim3(24, 24), blk, 0, stream>>>(Wk, WqkvT + 768 * 768, 768, 768);
  transpose_cast<<<dim3(24, 24), blk, 0, stream>>>(Wv, WqkvT + 2 * 768 * 768, 768, 768);
  transpose_cast<<<dim3(96, 24), blk, 0, stream>>>(W1, W1T, 768, 3072);
  transpose_cast<<<dim3(24, 96), blk, 0, stream>>>(W2, W2T, 3072, 768);
  pack_bias<<<dim3(9), blk, 0, stream>>>(bq, bk, bv, bqkv);

  // hn = LN(image)
  ln_kernel<<<NROWS / 4, blk, 0, stream>>>(image, ln_g, ln_b, hn);
  // qkv = hn @ Wqkv^T + bqkv   [65536, 2304] bf16   (grid 9x256, nwg%8==0)
  gemm256<2><<<dim3(QKV_N / 256, NROWS / 256), blk512, 0, stream>>>(
      hn, WqkvT, bqkv, qkv, nullptr, nullptr, NROWS, QKV_N, E_DIM);
  // x = image + attn -> d_out
  attn_kernel<<<1024 * HEADS, blk, 0, stream>>>(qkv, image, out);
  // hn2 = LN(x)  (reuse hn)
  ln_kernel<<<NROWS / 4, blk, 0, stream>>>(out, ln_g, ln_b, hn);
  // h1 = gelu(hn2 @ W1 + b1)   (grid 12x256)
  gemm256<0><<<dim3(HID_DIM / 256, NROWS / 256), blk512, 0, stream>>>(
      hn, W1T, b1, h1, nullptr, nullptr, NROWS, HID_DIM, E_DIM);
  // out = x + (h1 @ W2 + b2)   (grid 3x256)
  gemm256<1><<<dim3(E_DIM / 256, NROWS / 256), blk512, 0, stream>>>(
      h1, W2T, b2, nullptr, out, out, NROWS, E_DIM, HID_DIM);
}

// Round 2
// 1569.467 us; speedup vs baseline: 1.2463x; 1.0250x over previous
//
#include <hip/hip_runtime.h>
#include <hip/hip_bf16.h>
#include <cstdint>
#include <cstddef>

// ---------------------------------------------------------------------------
// ViT block: x = image + attn(LN(image)); out = x + MLP(LN(x))
// B=1024 S=64 E=768 H=12 DH=64 HID=3072.  All GEMMs bf16 MFMA 16x16x32,
// fp32 accumulate; residual spine fp32.
// R4: minimal-barrier K-loop (2 barriers/K-tile, AITER-style ~32 MFMA per
// barrier).  R3's 8-barrier phase lockstep exposed LDS latency serially
// (measured 5.2k cyc/K-tile vs 2.5k MFMA floor).  Now:
//   tile g: stage nxt{Ah1,Bh0,Bh1}(g+1) -> read all 24 frags (compiler
//   counted lgkm) -> MFMA h0 (32) -> lgkm0+barrier -> stage cur.h0<-Ah0(g+2)
//   -> MFMA h1 (32) -> lgkm0 + vmcnt(2) + barrier.
// vmcnt never 0 mid-loop (T4); T1 XCD swizzle; T2 both-sides LDS swizzle;
// T5 setprio around MFMA clusters.
// ---------------------------------------------------------------------------

typedef __bf16 bf16;
typedef __bf16 bf16x8 __attribute__((ext_vector_type(8)));
typedef __bf16 bf16x4 __attribute__((ext_vector_type(4)));
typedef float  f32x4  __attribute__((ext_vector_type(4)));

#define LDS_ASYNC16(lds, g)                                                     \
  __builtin_amdgcn_global_load_lds(                                             \
      (const __attribute__((address_space(1))) void*)(g),                       \
      (__attribute__((address_space(3))) void*)(lds), 16, 0, 0)

#define NROWS 65536   // B*S
#define E_DIM 768
#define HID_DIM 3072
#define HEADS 12
#define QKV_N 2304    // 3*E

// ---------------------------------------------------------------------------
// transpose + fp32->bf16 cast:  in [K,N] row-major -> out [N,K] row-major
// ---------------------------------------------------------------------------
__global__ __launch_bounds__(256) void transpose_cast(
    const float* __restrict__ in, bf16* __restrict__ out, int K, int N) {
  __shared__ float tile[32][33];
  int tx = threadIdx.x & 31, ty = threadIdx.x >> 5;  // 32 x 8
  int n0 = blockIdx.x * 32, k0 = blockIdx.y * 32;
#pragma unroll
  for (int i = 0; i < 4; ++i)
    tile[ty + 8 * i][tx] = in[(size_t)(k0 + ty + 8 * i) * N + n0 + tx];
  __syncthreads();
#pragma unroll
  for (int i = 0; i < 4; ++i)
    out[(size_t)(n0 + ty + 8 * i) * K + k0 + tx] = (bf16)tile[tx][ty + 8 * i];
}

__global__ __launch_bounds__(256) void pack_bias(
    const float* __restrict__ bq, const float* __restrict__ bk,
    const float* __restrict__ bv, float* __restrict__ o) {
  int i = blockIdx.x * 256 + threadIdx.x;  // grid 9 -> 2304
  const float* src = i < 768 ? bq : (i < 1536 ? bk : bv);
  o[i] = src[i & 767];  // 768-aligned sections
}

// ---------------------------------------------------------------------------
// LayerNorm over E=768, one wave per row, fp32 in -> bf16 out
// ---------------------------------------------------------------------------
__global__ __launch_bounds__(256) void ln_kernel(
    const float* __restrict__ x, const float* __restrict__ gam,
    const float* __restrict__ bet, bf16* __restrict__ out) {
  int row  = blockIdx.x * 4 + (threadIdx.x >> 6);
  int lane = threadIdx.x & 63;
  const float4* xr = (const float4*)(x + (size_t)row * E_DIM);
  float4 v[3];
  float s = 0.f, ss = 0.f;
#pragma unroll
  for (int i = 0; i < 3; ++i) {
    v[i] = xr[lane + 64 * i];
    s  += v[i].x + v[i].y + v[i].z + v[i].w;
    ss += v[i].x * v[i].x + v[i].y * v[i].y + v[i].z * v[i].z + v[i].w * v[i].w;
  }
#pragma unroll
  for (int m = 1; m < 64; m <<= 1) {
    s  += __shfl_xor(s, m);
    ss += __shfl_xor(ss, m);
  }
  float mean = s * (1.f / 768.f);
  float var  = ss * (1.f / 768.f) - mean * mean;
  float rstd = rsqrtf(var + 1e-6f);
  bf16x4* o = (bf16x4*)(out + (size_t)row * E_DIM);
#pragma unroll
  for (int i = 0; i < 3; ++i) {
    float4 g4 = ((const float4*)gam)[lane + 64 * i];
    float4 b4 = ((const float4*)bet)[lane + 64 * i];
    bf16x4 r;
    r[0] = (bf16)((v[i].x - mean) * rstd * g4.x + b4.x);
    r[1] = (bf16)((v[i].y - mean) * rstd * g4.y + b4.y);
    r[2] = (bf16)((v[i].z - mean) * rstd * g4.z + b4.z);
    r[3] = (bf16)((v[i].w - mean) * rstd * g4.w + b4.w);
    o[lane + 64 * i] = r;
  }
}

// ---------------------------------------------------------------------------
// Lean attention per (b,h): q,k,v tiles from packed qkv buffer, scores MFMA,
// softmax, V@P MFMA, +image residual.  S==DH==64 reshape identity:
// x_flat[b*49152 + h*4096 + s*64 + t] = image + attn[b,h,s,t]
// ---------------------------------------------------------------------------
__global__ __launch_bounds__(256) void attn_kernel(
    const bf16* __restrict__ qkv, const float* __restrict__ image,
    float* __restrict__ xout) {
  __shared__ __align__(16) bf16 qs[64 * 72];  // pad 72: 2-way = free
  __shared__ __align__(16) bf16 ks[64 * 72];
  __shared__ __align__(16) bf16 vs[64 * 72];
  __shared__ __align__(16) bf16 pT[64 * 72];

  const int t = threadIdx.x, w = t >> 6, lane = t & 63;
  const int quad = lane >> 4, l15 = lane & 15;
  const int h = blockIdx.x % HEADS, b = blockIdx.x / HEADS;

  const bf16* base = qkv + (size_t)(b * 64) * QKV_N + h * 64;
#pragma unroll
  for (int i = 0; i < 2; ++i) {
    int slot = i * 256 + t;          // 0..511
    int row = slot >> 3, c = (slot & 7) * 8;
    size_t go = (size_t)row * QKV_N + c;
    *(bf16x8*)&qs[row * 72 + c] = *(const bf16x8*)&base[go];
    *(bf16x8*)&ks[row * 72 + c] = *(const bf16x8*)&base[go + 768];
    *(bf16x8*)&vs[row * 72 + c] = *(const bf16x8*)&base[go + 1536];
  }
  __syncthreads();

  // scores = q @ k^T; wave w owns rows w*16..+16
  f32x4 sc[4] = {};
#pragma unroll
  for (int kk = 0; kk < 2; ++kk) {
    bf16x8 af = *(const bf16x8*)&qs[(w * 16 + l15) * 72 + kk * 32 + quad * 8];
#pragma unroll
    for (int ni = 0; ni < 4; ++ni) {
      bf16x8 bfr = *(const bf16x8*)&ks[(ni * 16 + l15) * 72 + kk * 32 + quad * 8];
      sc[ni] = __builtin_amdgcn_mfma_f32_16x16x32_bf16(af, bfr, sc[ni], 0, 0, 0);
    }
  }

  // scale by 1/sqrt(E) then softmax along t (row in one quad x 4 regs)
  const float inv_sqrt_e = 0.03608439182435161f;
#pragma unroll
  for (int r = 0; r < 4; ++r) {
    float s0 = sc[0][r] * inv_sqrt_e, s1 = sc[1][r] * inv_sqrt_e;
    float s2 = sc[2][r] * inv_sqrt_e, s3 = sc[3][r] * inv_sqrt_e;
    float mx = fmaxf(fmaxf(s0, s1), fmaxf(s2, s3));
    mx = fmaxf(mx, __shfl_xor(mx, 1));
    mx = fmaxf(mx, __shfl_xor(mx, 2));
    mx = fmaxf(mx, __shfl_xor(mx, 4));
    mx = fmaxf(mx, __shfl_xor(mx, 8));
    float e0 = __expf(s0 - mx), e1 = __expf(s1 - mx);
    float e2 = __expf(s2 - mx), e3 = __expf(s3 - mx);
    float sm = e0 + e1 + e2 + e3;
    sm += __shfl_xor(sm, 1);
    sm += __shfl_xor(sm, 2);
    sm += __shfl_xor(sm, 4);
    sm += __shfl_xor(sm, 8);
    float inv = 1.f / sm;
    sc[0][r] = e0 * inv; sc[1][r] = e1 * inv;
    sc[2][r] = e2 * inv; sc[3][r] = e3 * inv;
  }

  // store P transposed: pT[t][s]
#pragma unroll
  for (int ni = 0; ni < 4; ++ni) {
    int tc = ni * 16 + l15;
#pragma unroll
    for (int r = 0; r < 4; ++r) {
      int s = w * 16 + quad * 4 + r;
      pT[tc * 72 + s] = (bf16)sc[ni][r];
    }
  }
  __syncthreads();

  // attn[s][t] = sum_d v[s][d] * P[d][t]
  f32x4 ao[4] = {};
#pragma unroll
  for (int kk = 0; kk < 2; ++kk) {
    bf16x8 af = *(const bf16x8*)&vs[(w * 16 + l15) * 72 + kk * 32 + quad * 8];
#pragma unroll
    for (int ni = 0; ni < 4; ++ni) {
      bf16x8 bfr = *(const bf16x8*)&pT[(ni * 16 + l15) * 72 + kk * 32 + quad * 8];
      ao[ni] = __builtin_amdgcn_mfma_f32_16x16x32_bf16(af, bfr, ao[ni], 0, 0, 0);
    }
  }

  size_t base_o = (size_t)b * 49152 + (size_t)h * 4096;
#pragma unroll
  for (int ni = 0; ni < 4; ++ni) {
    int tc = ni * 16 + l15;
#pragma unroll
    for (int r = 0; r < 4; ++r) {
      int s = w * 16 + quad * 4 + r;
      size_t off = base_o + (size_t)s * 64 + tc;
      xout[off] = image[off] + ao[ni][r];
    }
  }
}

// ---------------------------------------------------------------------------
// fast GELU: tanh form, robust at +-inf (no inf/inf)
// ---------------------------------------------------------------------------
__device__ inline float gelu_f(float x) {
  float u = x * (0.7978845608028654f + 0.0356774081f * x * x);
  float e = __expf(2.f * u);
  float th = 1.f - 2.f / (e + 1.f);
  return 0.5f * x * (1.f + th);
}

__device__ __forceinline__ f32x4 mfma8(bf16x8 a, bf16x8 b, f32x4 c) {
  return __builtin_amdgcn_mfma_f32_16x16x32_bf16(a, b, c, 0, 0, 0);
}

#define LDF(P, OFF) (*(const bf16x8*)((P) + (OFF)))

// ---------------------------------------------------------------------------
// 256x256 GEMM, minimal-barrier pipeline:  C[M,N] = A[M,K] @ B^T
// (B stored [N,K] bf16).  Requires M%256==0, N%256==0, K%64==0, K>=192,
// grid = (N/256, M/256), nwg%8==0.
// EPI 0: bias+GELU->bf16.  1: bias+resid->f32.  2: bias->bf16.
// ---------------------------------------------------------------------------
template <int EPI>
__global__ __launch_bounds__(512) void gemm256(
    const bf16* __restrict__ A, const bf16* __restrict__ B,
    const float* __restrict__ bias, bf16* __restrict__ outb, float* outf,
    const float* resid, int M, int N, int K) {
  __shared__ __align__(16) char lds[131072];  // A: 2x32KB @0, B: 2x32KB @64K
  const int t = threadIdx.x;
  const int wq = t >> 6, lane = t & 63;
  const int quad = lane >> 4, l15 = lane & 15;
  const int wm = wq >> 2, wn = wq & 3;  // 2 x 4 wave grid

  // T1: XCD-aware bijective swizzle (nwg % 8 == 0 for all launch shapes here)
  const int Ntile = (int)gridDim.x;
  const int nwg = Ntile * (int)gridDim.y;
  const int flat = (int)blockIdx.y * Ntile + (int)blockIdx.x;
  const int id2 = (flat & 7) * (nwg >> 3) + (flat >> 3);
  const int bn = id2 % Ntile, bm = id2 / Ntile;

  const int NT = K >> 6;  // K-tiles of 64
  const size_t rowK = (size_t)K;

  // Staging: per-thread pre-swizzled GLOBAL source (linear LDS dest).
  // dst byte t*16 -> tile row t>>3, slot t&7; phys slot holds logical
  // slot (t&7)^(row&7), so fetch that column from global.
  const int tr = t >> 3, ts = t & 7;
  const bf16* aSrc = A + ((size_t)bm * 256 + tr) * rowK + ((ts ^ (tr & 7)) << 3);
  const bf16* bSrc = B + ((size_t)bn * 256 + tr) * rowK + ((ts ^ (tr & 7)) << 3);

  char* ldsA = (char*)lds;
  char* ldsB = (char*)lds + 65536;
  const int stDst = wq * 1024;  // wave-uniform LDS base piece

  // stage one 128-row half-tile (2 x global_load_lds w=16; 512 thr x 16B x 2)
#define STAGE_H(LB, BUFP, H, SRC, KT)                                           \
  do {                                                                          \
    LDS_ASYNC16((LB) + (BUFP) * 32768 + ((H) * 128 + 0) * 128 + stDst,          \
                (SRC) + (size_t)((H) * 128 + 0) * rowK + (size_t)(KT) * 64);    \
    LDS_ASYNC16((LB) + (BUFP) * 32768 + ((H) * 128 + 64) * 128 + stDst,         \
                (SRC) + (size_t)((H) * 128 + 64) * rowK + (size_t)(KT) * 64);   \
  } while (0)

  // prologue: tile 0 fully -> buf0 (8 loads), then Ah0(1) -> buf1 (2 loads).
  // vmcnt(2) = tile0 landed, Ah0(1) in flight: the steady-state invariant.
  STAGE_H(ldsA, 0, 0, aSrc, 0);
  STAGE_H(ldsA, 0, 1, aSrc, 0);
  STAGE_H(ldsB, 0, 0, bSrc, 0);
  STAGE_H(ldsB, 0, 1, bSrc, 0);
  STAGE_H(ldsA, 1, 0, aSrc, 1);
  asm volatile("s_waitcnt vmcnt(2)" ::: "memory");
  __builtin_amdgcn_s_barrier();

  // T2 read swizzle: logical 16B slot (kk*4+quad) ^ (row&7); row&7 == l15&7.
  const int sx = l15 & 7;
  const int c0 = (quad ^ sx) << 4;        // kk=0
  const int c1 = ((4 + quad) ^ sx) << 4;  // kk=1
  // A rows: half h at (h*128 + wm*64 + mi*16 + l15); *128 B/row
  const int arow = (wm * 64 + l15) * 128;
  const int brow = (wn * 64 + l15) * 128;

  f32x4 acc[8][4] = {};

  for (int g = 0; g < NT; ++g) {
    const int bufp = g & 1, nx = bufp ^ 1;
    const char* Ab = ldsA + bufp * 32768;
    const char* Bb = ldsB + bufp * 32768;

    // stage next tile's non-conflicting halves into the OTHER buffer
    // (its previous contents were fully consumed before last tile's barrier)
    if (g + 1 < NT) {
      STAGE_H(ldsA, nx, 1, aSrc, g + 1);
      STAGE_H(ldsB, nx, 0, bSrc, g + 1);
      STAGE_H(ldsB, nx, 1, bSrc, g + 1);
    }

    // all 24 fragment reads up front; compiler inserts counted lgkm waits
    bf16x8 bReg[4][2], aF0[4][2], aF1[4][2];
#pragma unroll
    for (int ni = 0; ni < 4; ++ni) {
      bReg[ni][0] = LDF(Bb, brow + ni * 2048 + c0);
      bReg[ni][1] = LDF(Bb, brow + ni * 2048 + c1);
    }
#pragma unroll
    for (int mi = 0; mi < 4; ++mi) {
      aF0[mi][0] = LDF(Ab, arow + mi * 2048 + c0);
      aF0[mi][1] = LDF(Ab, arow + mi * 2048 + c1);
    }
#pragma unroll
    for (int mi = 0; mi < 4; ++mi) {
      aF1[mi][0] = LDF(Ab, arow + 16384 + mi * 2048 + c0);
      aF1[mi][1] = LDF(Ab, arow + 16384 + mi * 2048 + c1);
    }

    // MFMA half 0 (rows 0..127 of the tile)
    __builtin_amdgcn_s_setprio(1);
#pragma unroll
    for (int mi = 0; mi < 4; ++mi)
#pragma unroll
      for (int ni = 0; ni < 4; ++ni) {
        acc[mi][ni] = mfma8(aF0[mi][0], bReg[ni][0], acc[mi][ni]);
        acc[mi][ni] = mfma8(aF0[mi][1], bReg[ni][1], acc[mi][ni]);
      }
    __builtin_amdgcn_s_setprio(0);

    // all waves done reading cur.h0 (own reads complete + barrier) ->
    // safe to overwrite cur.h0 with Ah0(g+2)
    asm volatile("s_waitcnt lgkmcnt(0)" ::: "memory");
    __builtin_amdgcn_s_barrier();
    if (g + 2 < NT) STAGE_H(ldsA, bufp, 0, aSrc, g + 2);

    // MFMA half 1 (rows 128..255)
    __builtin_amdgcn_s_setprio(1);
#pragma unroll
    for (int mi = 0; mi < 4; ++mi)
#pragma unroll
      for (int ni = 0; ni < 4; ++ni) {
        acc[4 + mi][ni] = mfma8(aF1[mi][0], bReg[ni][0], acc[4 + mi][ni]);
        acc[4 + mi][ni] = mfma8(aF1[mi][1], bReg[ni][1], acc[4 + mi][ni]);
      }
    __builtin_amdgcn_s_setprio(0);

    // end-of-tile: own reads done (free), counted vmcnt keeps Ah0(g+2) in
    // flight; barrier releases next tile (which overwrites cur.h1 / cur.B)
    asm volatile("s_waitcnt lgkmcnt(0)" ::: "memory");
    if (g < NT - 2)
      asm volatile("s_waitcnt vmcnt(2)" ::: "memory");
    else if (g == NT - 2)
      asm volatile("s_waitcnt vmcnt(0)" ::: "memory");
    __builtin_amdgcn_s_barrier();
  }
#undef STAGE_H

  // epilogue: C[row,col], row = bm*256 + half*128 + wm*64 + (mi&3)*16+quad*4+r
  const int row0 = bm * 256 + wm * 64 + quad * 4;
  const int col0 = bn * 256 + wn * 64 + l15;
#pragma unroll
  for (int mi = 0; mi < 8; ++mi) {
    const int rbase = row0 + (mi >> 2) * 128 + (mi & 3) * 16;
#pragma unroll
    for (int ni = 0; ni < 4; ++ni) {
      const int col = col0 + ni * 16;
      const float bc = bias[col];
#pragma unroll
      for (int r = 0; r < 4; ++r) {
        const int row = rbase + r;
        const float v = acc[mi][ni][r] + bc;
        const size_t off = (size_t)row * N + col;
        if (EPI == 0)      outb[off] = (bf16)gelu_f(v);
        else if (EPI == 1) outf[off] = resid[off] + v;
        else               outb[off] = (bf16)v;
      }
    }
  }
}

// ---------------------------------------------------------------------------
extern "C" void kernel_launch(void* const* d_in, const int* in_sizes, int n_in,
                              void* d_out, int out_size, void* d_ws,
                              size_t ws_size, hipStream_t stream) {
  const float* image = (const float*)d_in[0];
  const float* ln_g  = (const float*)d_in[1];
  const float* ln_b  = (const float*)d_in[2];
  const float* Wq    = (const float*)d_in[3];
  const float* bq    = (const float*)d_in[4];
  const float* Wk    = (const float*)d_in[5];
  const float* bk    = (const float*)d_in[6];
  const float* Wv    = (const float*)d_in[7];
  const float* bv    = (const float*)d_in[8];
  const float* W1    = (const float*)d_in[9];
  const float* b1    = (const float*)d_in[10];
  const float* W2    = (const float*)d_in[11];
  const float* b2    = (const float*)d_in[12];
  float* out = (float*)d_out;

  char* ws = (char*)d_ws;
  bf16* hn   = (bf16*)ws;  ws += (size_t)NROWS * E_DIM * 2;      // 100.7 MB
  // h1 (65536x3072 bf16, 402 MB) and qkv (65536x2304 bf16, 302 MB) have
  // disjoint live ranges -> alias the same region.
  bf16* h1   = (bf16*)ws;
  bf16* qkv  = (bf16*)ws;  ws += (size_t)NROWS * HID_DIM * 2;
  bf16* WqkvT = (bf16*)ws; ws += (size_t)QKV_N * E_DIM * 2;      // packed [2304,768]
  bf16* W1T  = (bf16*)ws;  ws += (size_t)E_DIM * HID_DIM * 2;
  bf16* W2T  = (bf16*)ws;  ws += (size_t)E_DIM * HID_DIM * 2;
  float* bqkv = (float*)ws; ws += QKV_N * 4;

  dim3 blk(256);
  dim3 blk512(512);
  // weights -> bf16 [N,K]; Wq|Wk|Wv packed into one [2304,768]
  transpose_cast<<<dim3(24, 24), blk, 0, stream>>>(Wq, WqkvT, 768, 768);
  transpose_cast<<<dim3(24, 24), blk, 0, stream>>>(Wk, WqkvT + 768 * 768, 768, 768);
  transpose_cast<<<dim3(24, 24), blk, 0, stream>>>(Wv, WqkvT + 2 * 768 * 768, 768, 768);
  transpose_cast<<<dim3(96, 24), blk, 0, stream>>>(W1, W1T, 768, 3072);
  transpose_cast<<<dim3(24, 96), blk, 0, stream>>>(W2, W2T, 3072, 768);
  pack_bias<<<dim3(9), blk, 0, stream>>>(bq, bk, bv, bqkv);

  // hn = LN(image)
  ln_kernel<<<NROWS / 4, blk, 0, stream>>>(image, ln_g, ln_b, hn);
  // qkv = hn @ Wqkv^T + bqkv   [65536, 2304] bf16   (grid 9x256, nwg%8==0)
  gemm256<2><<<dim3(QKV_N / 256, NROWS / 256), blk512, 0, stream>>>(
      hn, WqkvT, bqkv, qkv, nullptr, nullptr, NROWS, QKV_N, E_DIM);
  // x = image + attn -> d_out
  attn_kernel<<<1024 * HEADS, blk, 0, stream>>>(qkv, image, out);
  // hn2 = LN(x)  (reuse hn)
  ln_kernel<<<NROWS / 4, blk, 0, stream>>>(out, ln_g, ln_b, hn);
  // h1 = gelu(hn2 @ W1 + b1)   (grid 12x256)
  gemm256<0><<<dim3(HID_DIM / 256, NROWS / 256), blk512, 0, stream>>>(
      hn, W1T, b1, h1, nullptr, nullptr, NROWS, HID_DIM, E_DIM);
  // out = x + (h1 @ W2 + b2)   (grid 3x256)
  gemm256<1><<<dim3(E_DIM / 256, NROWS / 256), blk512, 0, stream>>>(
      h1, W2T, b2, nullptr, out, out, NROWS, E_DIM, HID_DIM);
}